// Round 1
// 321.060 us; speedup vs baseline: 1.0082x; 1.0082x over previous
//
#include <hip/hip_runtime.h>
#include <hip/hip_bf16.h>
#include <stdint.h>

// ============================================================================
// MultiAttentionWithGating — compression branch (_kc/_vc) is DEAD CODE.
// Pipeline: qkv = x@W_attn^T ; causal SDPA (16 heads, hs=64) ; out = y@W_proj^T
// Inputs fp32 (runtime-probed); internal bf16 MFMA, fp32 accum.
//
// ROUND 9 (attn 114us, latency-bound: all pipes <31%, occupancy 14%):
//  - XCD/CU load-balance remap of q-block index. Old qb = 15 - x put only
//    qb in {15-c, 7-c+8} on XCD c (x round-robins XCDs) -> heavy CUs carried
//    ~96 tile-units vs 68 balanced; light CUs idled (occupancy 14%).
//    New map qb = (x<8) ? 15-x : x-8 gives qb(x)+qb(x+8)=15: every XCD's
//    stream alternates {long,short} = 34 tiles/pair; any 4 consecutive
//    blocks on a CU sum to exactly 68 tile-units. Robust to round-robin or
//    chunked XCD assignment.
//  - Everything else unchanged from round 8 for clean attribution.
// ============================================================================

typedef __bf16 bf16x8 __attribute__((ext_vector_type(8)));
typedef float f32x4 __attribute__((ext_vector_type(4)));
typedef __hip_bfloat16 bf16;

#define B_ 4
#define T_ 2048
#define C_ 1024
#define NH_ 16
#define HS_ 64
#define NEG_BIG (-30000.0f)
#define SCALE_LOG2E 0.180336880111f  // (1/sqrt(64)) * log2(e)

// Wave-uniform dtype probe on x (fp32 vs bf16), verified round 4.
__device__ __forceinline__ bool detect_fp32(const unsigned short* px) {
  const int lane = threadIdx.x & 63;
  const unsigned short u = px[2 * lane];
  const int e = (u >> 7) & 0xff;
  const bool plausible = (e >= 117) && (e <= 137);
  return __popcll(__ballot(plausible)) < 32;
}

// async global->LDS 16B per lane (m97). LDS dest: wave-uniform base + lane*16.
__device__ __forceinline__ void load_lds16(const bf16* g, bf16* l) {
  __builtin_amdgcn_global_load_lds(
      (const __attribute__((address_space(1))) void*)(uintptr_t)g,
      (__attribute__((address_space(3))) void*)(uintptr_t)l, 16, 0, 0);
}

// fp32 load of 8 elements -> 8 bf16 packed in uint4.
__device__ __forceinline__ uint4 ld8f(const void* base, size_t elt) {
  const float* fp = (const float*)base + elt;
  float4 f0 = *(const float4*)(fp);
  float4 f1 = *(const float4*)(fp + 4);
  union { bf16 h[8]; uint4 u; } r;
  r.h[0] = __float2bfloat16(f0.x); r.h[1] = __float2bfloat16(f0.y);
  r.h[2] = __float2bfloat16(f0.z); r.h[3] = __float2bfloat16(f0.w);
  r.h[4] = __float2bfloat16(f1.x); r.h[5] = __float2bfloat16(f1.y);
  r.h[6] = __float2bfloat16(f1.z); r.h[7] = __float2bfloat16(f1.w);
  return r.u;
}

// ----------------------------------------------------------------------------
// One-shot fp32->bf16 conversion of x, W_attn, W_proj (8 elems/thread).
// ----------------------------------------------------------------------------
__global__ __launch_bounds__(256) void convert3(
    const void* __restrict__ x, const void* __restrict__ wa,
    const void* __restrict__ wp, bf16* __restrict__ xb, bf16* __restrict__ wab,
    bf16* __restrict__ wpb, const unsigned short* __restrict__ probe) {
  const bool f32 = detect_fp32(probe);
  int blk = blockIdx.x;
  const void* src;
  bf16* dst;
  if (blk < 4096) {
    src = x; dst = xb;
  } else if (blk < 4096 + 1536) {
    blk -= 4096; src = wa; dst = wab;
  } else {
    blk -= 4096 + 1536; src = wp; dst = wpb;
  }
  const size_t i = ((size_t)blk * 256 + threadIdx.x) * 8;
  if (f32)
    *(uint4*)(dst + i) = ld8f(src, i);
  else
    *(uint4*)(dst + i) = *(const uint4*)((const bf16*)src + i);
}

// ----------------------------------------------------------------------------
// gemm_bt (round 7, unchanged): 128x128 tile, BK=32, global_load_lds staging
// on the bf16 path, fp32 reg-staging fallback.
// ----------------------------------------------------------------------------
template <int IN_MODE, int OUT_MODE>
__global__ __launch_bounds__(256, 2) void gemm_bt(
    const void* __restrict__ A, const void* __restrict__ B, void* __restrict__ C,
    bf16* __restrict__ k_ws, bf16* __restrict__ v_ws,
    const unsigned short* __restrict__ in_probe,
    const unsigned short* __restrict__ out_probe, int M, int N, int K) {
  __shared__ bf16 As[128 * 32];
  __shared__ bf16 Bs[128 * 32];

  const bool f32b = in_probe ? detect_fp32(in_probe) : false;
  const bool f32a = (IN_MODE == 0) && f32b;
  const bool f32out =
      (OUT_MODE == 0) && (out_probe ? detect_fp32(out_probe) : false);

  const int tid = threadIdx.x;
  const int lane = tid & 63;
  const int wid = tid >> 6;
  const int quad = lane >> 4;
  const int col = lane & 15;
  const int m0 = blockIdx.y * 128;
  const int n0 = blockIdx.x * 128;
  const int wm = (wid >> 1) * 64;
  const int wn = (wid & 1) * 64;
  const bool vsec = (OUT_MODE == 1) && ((n0 >> 10) == 2);

  const size_t arow = (size_t)(m0 + (tid >> 2));
  const size_t brow = (size_t)(n0 + (tid >> 2));
  const int chunk = (tid & 3) * 8;

  f32x4 acc[4][4] = {};

  for (int k0 = 0; k0 < K; k0 += 32) {
    const bf16* ap0;
    const bf16* ap1;
    if (IN_MODE == 0) {
      ap0 = (const bf16*)A + arow * K + chunk + k0;
      ap1 = (const bf16*)A + (arow + 64) * K + chunk + k0;
    } else {
      const int b = m0 >> 11;
      const int tloc = (m0 & 2047) + (tid >> 2);
      const size_t aoff = ((((size_t)b * NH_) + (k0 >> 6)) * T_ + tloc) * HS_ +
                          (k0 & 32) + chunk;
      ap0 = (const bf16*)A + aoff;
      ap1 = (const bf16*)A + aoff + (size_t)64 * HS_;
    }

    uint4 a0, a1, b0, b1;
    if (f32a) {
      a0 = ld8f(A, arow * K + chunk + k0);
      a1 = ld8f(A, (arow + 64) * K + chunk + k0);
    }
    if (f32b) {
      b0 = ld8f(B, brow * K + chunk + k0);
      b1 = ld8f(B, (brow + 64) * K + chunk + k0);
    }

    __syncthreads();
    if (f32a) {
      *(uint4*)(As + tid * 8) = a0;
      *(uint4*)(As + 2048 + tid * 8) = a1;
    } else {
      load_lds16(ap0, As + tid * 8);
      load_lds16(ap1, As + 2048 + tid * 8);
    }
    if (f32b) {
      *(uint4*)(Bs + tid * 8) = b0;
      *(uint4*)(Bs + 2048 + tid * 8) = b1;
    } else {
      load_lds16((const bf16*)B + brow * K + chunk + k0, Bs + tid * 8);
      load_lds16((const bf16*)B + (brow + 64) * K + chunk + k0,
                 Bs + 2048 + tid * 8);
    }
    __syncthreads();

    bf16x8 af[4], bfr[4];
#pragma unroll
    for (int t = 0; t < 4; ++t) {
      af[t] = *(const bf16x8*)(As + (wm + t * 16 + col) * 32 + quad * 8);
      bfr[t] = *(const bf16x8*)(Bs + (wn + t * 16 + col) * 32 + quad * 8);
    }
    if (vsec) {
#pragma unroll
      for (int tm = 0; tm < 4; ++tm)
#pragma unroll
        for (int tn = 0; tn < 4; ++tn)
          acc[tm][tn] = __builtin_amdgcn_mfma_f32_16x16x32_bf16(
              bfr[tn], af[tm], acc[tm][tn], 0, 0, 0);
    } else {
#pragma unroll
      for (int tm = 0; tm < 4; ++tm)
#pragma unroll
        for (int tn = 0; tn < 4; ++tn)
          acc[tm][tn] = __builtin_amdgcn_mfma_f32_16x16x32_bf16(
              af[tm], bfr[tn], acc[tm][tn], 0, 0, 0);
    }
  }

  if (OUT_MODE == 0) {
#pragma unroll
    for (int tm = 0; tm < 4; ++tm) {
      const int mrow = m0 + wm + tm * 16 + quad * 4;
#pragma unroll
      for (int tn = 0; tn < 4; ++tn) {
        const int ncol = n0 + wn + tn * 16 + col;
#pragma unroll
        for (int r = 0; r < 4; ++r) {
          if (f32out)
            ((float*)C)[(size_t)(mrow + r) * N + ncol] = acc[tm][tn][r];
          else
            ((bf16*)C)[(size_t)(mrow + r) * N + ncol] =
                __float2bfloat16(acc[tm][tn][r]);
        }
      }
    }
  } else if (vsec) {
    const int b = m0 >> 11;
#pragma unroll
    for (int tm = 0; tm < 4; ++tm) {
      const int tloc = (m0 & 2047) + wm + tm * 16 + col;
#pragma unroll
      for (int tn = 0; tn < 4; ++tn) {
        const int vch = (n0 & (C_ - 1)) + wn + tn * 16 + quad * 4;
#pragma unroll
        for (int r = 0; r < 4; ++r) {
          const int h = (vch + r) >> 6, d = (vch + r) & 63;
          v_ws[(((size_t)b * NH_ + h) * HS_ + d) * T_ + tloc] =
              __float2bfloat16(acc[tm][tn][r]);
        }
      }
    }
  } else {
    const int sect = n0 >> 10;  // 0:q 1:k
    bf16* dst = (sect == 0) ? (bf16*)C : k_ws;
#pragma unroll
    for (int tm = 0; tm < 4; ++tm) {
      const int mrow = m0 + wm + tm * 16 + quad * 4;
#pragma unroll
      for (int tn = 0; tn < 4; ++tn) {
        const int c = (n0 + wn + tn * 16 + col) & (C_ - 1);
        const int h = c >> 6, d = c & 63;
#pragma unroll
        for (int r = 0; r < 4; ++r) {
          const int t = (mrow + r) & (T_ - 1);
          const int b = (mrow + r) >> 11;
          dst[(((size_t)b * NH_ + h) * T_ + t) * HS_ + d] =
              __float2bfloat16(acc[tm][tn][r]);
        }
      }
    }
  }
}

// ----------------------------------------------------------------------------
// MFMA flash attention (causal), fixed-max softmax. Block = one (b,h) x 128 q
// rows; 4 waves x 32 rows (2 subtiles of 16). S^T computed via operand-swapped
// MFMA: lane holds 4 consecutive keys for one q row -> P written as packed
// ds_write_b64 into per-wave [q][key] LDS; PV reads P as b128 A-frags.
// K/V fragments reused across both q-subtiles. No cross-lane reductions:
// fixed max 32 in accumulator init; l = P*ones via MFMA.
//
// q-block index is XCD/CU load-balanced: qb(x)+qb(x+8)=15 so every XCD gets
// alternating {long,short} pairs (34 tile-units each), every 4-consecutive
// dispatch window sums to 68 tile-units.
// ----------------------------------------------------------------------------
__global__ __launch_bounds__(256, 2) void attn(
    bf16* qy, const bf16* __restrict__ kws, const bf16* __restrict__ vws) {
  __shared__ bf16 Ks[64 * 72];      // [key][d]
  __shared__ bf16 Vs[64 * 72];      // [d][key]
  __shared__ bf16 Ps[4][32 * 72];   // per-wave P [32 q][64 k], stride 72

  const int tid = threadIdx.x;
  const int lane = tid & 63;
  const int w = tid >> 6;
  const int quad = lane >> 4;
  const int col = lane & 15;
  // Load-balance remap (round 9): pair long+short across XCD stride 8.
  const int gx = (int)gridDim.x;            // 16
  const int hx = gx >> 1;                   // 8
  const int x = (int)blockIdx.x;
  const int qb = (x < hx) ? (gx - 1 - x) : (x - hx);
  const int bh = blockIdx.y;
  const size_t head_off = (size_t)bh * T_ * HS_;

  // Q fragments for both subtiles, pre-scaled into exp2 domain
  const int qrow = qb * 128 + w * 32 + col;
  const bf16* qp = qy + head_off + (size_t)qrow * HS_ + quad * 8;
  bf16x8 qf0a = *(const bf16x8*)(qp);
  bf16x8 qf1a = *(const bf16x8*)(qp + 32);
  bf16x8 qf0b = *(const bf16x8*)(qp + 16 * HS_);
  bf16x8 qf1b = *(const bf16x8*)(qp + 16 * HS_ + 32);
#pragma unroll
  for (int j = 0; j < 8; ++j) {
    qf0a[j] = (__bf16)((float)qf0a[j] * SCALE_LOG2E);
    qf1a[j] = (__bf16)((float)qf1a[j] * SCALE_LOG2E);
    qf0b[j] = (__bf16)((float)qf0b[j] * SCALE_LOG2E);
    qf1b[j] = (__bf16)((float)qf1b[j] * SCALE_LOG2E);
  }

  bf16x8 onesf;
#pragma unroll
  for (int j = 0; j < 8; ++j) onesf[j] = (__bf16)1.0f;

  f32x4 oa[4] = {}, ob[4] = {};
  f32x4 lacca = {}, laccb = {};

  bf16* pw = &Ps[w][0];
  const int ntiles = 2 * (qb + 1);  // keys 0 .. qb*128+127

  // staging map: rows srow, srow+32; chunk sch
  const int srow = tid >> 3, sch = tid & 7;
  const bf16* kg = kws + head_off + (size_t)srow * HS_ + sch * 8;   // [key][d]
  const bf16* vg = vws + ((size_t)bh * HS_ + srow) * T_ + sch * 8;  // [d][key]
  bf16* kl0 = Ks + srow * 72 + sch * 8;
  bf16* kl1 = Ks + (srow + 32) * 72 + sch * 8;
  bf16* vl0 = Vs + srow * 72 + sch * 8;
  bf16* vl1 = Vs + (srow + 32) * 72 + sch * 8;

  // prefetch tile 0
  uint4 kr0 = *(const uint4*)(kg);
  uint4 kr1 = *(const uint4*)(kg + (size_t)32 * HS_);
  uint4 vr0 = *(const uint4*)(vg);
  uint4 vr1 = *(const uint4*)(vg + (size_t)32 * T_);

  const int qga = qb * 128 + w * 32 + col;  // subtile-a global q row
  const int diag_start = 2 * qb;            // tiles >= this need masking

  for (int kt = 0; kt < ntiles; ++kt) {
    const int k0 = kt * 64;
    __syncthreads();
    *(uint4*)kl0 = kr0;
    *(uint4*)kl1 = kr1;
    *(uint4*)vl0 = vr0;
    *(uint4*)vl1 = vr1;
    __syncthreads();
    if (kt + 1 < ntiles) {  // prefetch next tile during compute
      kg += (size_t)64 * HS_;
      vg += 64;
      kr0 = *(const uint4*)(kg);
      kr1 = *(const uint4*)(kg + (size_t)32 * HS_);
      vr0 = *(const uint4*)(vg);
      vr1 = *(const uint4*)(vg + (size_t)32 * T_);
    }

    // ---- S^T - 32 = (K Q^T) - 32 : lane -> (key=quad*4+r, q=col) ----
    f32x4 sa[4], sb[4];
#pragma unroll
    for (int nt = 0; nt < 4; ++nt) {
      const bf16* kp = Ks + (nt * 16 + col) * 72 + quad * 8;
      bf16x8 kf0 = *(const bf16x8*)(kp);
      bf16x8 kf1 = *(const bf16x8*)(kp + 32);
      f32x4 a = {-32.0f, -32.0f, -32.0f, -32.0f};
      a = __builtin_amdgcn_mfma_f32_16x16x32_bf16(kf0, qf0a, a, 0, 0, 0);
      a = __builtin_amdgcn_mfma_f32_16x16x32_bf16(kf1, qf1a, a, 0, 0, 0);
      sa[nt] = a;
      f32x4 b = {-32.0f, -32.0f, -32.0f, -32.0f};
      b = __builtin_amdgcn_mfma_f32_16x16x32_bf16(kf0, qf0b, b, 0, 0, 0);
      b = __builtin_amdgcn_mfma_f32_16x16x32_bf16(kf1, qf1b, b, 0, 0, 0);
      sb[nt] = b;
    }

    // ---- causal mask (only tiles overlapping the diagonal) ----
    // NOTE: S^T indices — key = k0 + nt*16 + quad*4 + r ; q = qga(+16)
    if (kt >= diag_start) {
#pragma unroll
      for (int nt = 0; nt < 4; ++nt) {
        const int key = k0 + nt * 16 + quad * 4;
#pragma unroll
        for (int r = 0; r < 4; ++r) {
          if (key + r > qga) sa[nt][r] = NEG_BIG;
          if (key + r > qga + 16) sb[nt][r] = NEG_BIG;
        }
      }
    }

    // ---- P = exp2(S-32): 4 consecutive keys/lane -> packed b64 writes ----
#pragma unroll
    for (int nt = 0; nt < 4; ++nt) {
      union { ushort u[4]; uint2 v; } pa, pb;
#pragma unroll
      for (int r = 0; r < 4; ++r) {
        pa.u[r] = __bfloat16_as_ushort(__float2bfloat16(exp2f(sa[nt][r])));
        pb.u[r] = __bfloat16_as_ushort(__float2bfloat16(exp2f(sb[nt][r])));
      }
      *(uint2*)(pw + col * 72 + nt * 16 + quad * 4) = pa.v;
      *(uint2*)(pw + (col + 16) * 72 + nt * 16 + quad * 4) = pb.v;
    }

    __asm__ __volatile__("s_waitcnt lgkmcnt(0)" ::: "memory");  // P visible

    // ---- O += P V ; l += P*ones (V-frags shared across subtiles) ----
#pragma unroll
    for (int half = 0; half < 2; ++half) {
      bf16x8 pfa = *(const bf16x8*)(pw + col * 72 + half * 32 + quad * 8);
      bf16x8 pfb = *(const bf16x8*)(pw + (col + 16) * 72 + half * 32 + quad * 8);
      lacca = __builtin_amdgcn_mfma_f32_16x16x32_bf16(pfa, onesf, lacca, 0, 0, 0);
      laccb = __builtin_amdgcn_mfma_f32_16x16x32_bf16(pfb, onesf, laccb, 0, 0, 0);
#pragma unroll
      for (int dt = 0; dt < 4; ++dt) {
        bf16x8 vf = *(const bf16x8*)(Vs + (dt * 16 + col) * 72 + half * 32 +
                                     quad * 8);
        oa[dt] = __builtin_amdgcn_mfma_f32_16x16x32_bf16(pfa, vf, oa[dt], 0, 0, 0);
        ob[dt] = __builtin_amdgcn_mfma_f32_16x16x32_bf16(pfb, vf, ob[dt], 0, 0, 0);
      }
    }
  }

  // ---- epilogue: y overwrites this wave's own q rows (head layout) ----
  float inva[4], invb[4];
#pragma unroll
  for (int r = 0; r < 4; ++r) {
    inva[r] = 1.0f / lacca[r];
    invb[r] = 1.0f / laccb[r];
  }
#pragma unroll
  for (int dt = 0; dt < 4; ++dt)
#pragma unroll
    for (int r = 0; r < 4; ++r) {
      const int qa = qb * 128 + w * 32 + quad * 4 + r;
      qy[head_off + (size_t)qa * HS_ + dt * 16 + col] =
          __float2bfloat16(oa[dt][r] * inva[r]);
      qy[head_off + (size_t)(qa + 16) * HS_ + dt * 16 + col] =
          __float2bfloat16(ob[dt][r] * invb[r]);
    }
}

// ----------------------------------------------------------------------------
extern "C" void kernel_launch(void* const* d_in, const int* in_sizes, int n_in,
                              void* d_out, int out_size, void* d_ws, size_t ws_size,
                              hipStream_t stream) {
  const void* x = d_in[0];       // [4,2048,1024] fp32 (probed)
  const void* W_attn = d_in[1];  // [3072,1024]
  const void* W_proj = d_in[2];  // [1024,1024]
  const unsigned short* probe = (const unsigned short*)d_in[0];
  // d_in[3..6]: dead code in the reference.

  const size_t qkv_elems = (size_t)B_ * NH_ * T_ * HS_;  // 8388608
  const size_t xe = (size_t)B_ * T_ * C_;                // 8388608
  const size_t wae = (size_t)3 * C_ * C_;                // 3145728
  const size_t wpe = (size_t)C_ * C_;                    // 1048576

  bf16* q_ws = (bf16*)d_ws;
  bf16* k_ws = q_ws + qkv_elems;
  bf16* v_ws = k_ws + qkv_elems;
  bf16* x_bf = v_ws + qkv_elems;
  bf16* wa_bf = x_bf + xe;
  bf16* wp_bf = wa_bf + wae;
  const size_t need = (3 * qkv_elems + xe + wae + wpe) * sizeof(bf16);  // 72 MiB

  const int M = B_ * T_;  // 8192

  if (ws_size >= need) {
    convert3<<<6144, 256, 0, stream>>>(x, W_attn, W_proj, x_bf, wa_bf, wp_bf,
                                       probe);
    gemm_bt<0, 1><<<dim3(3 * C_ / 128, M / 128), 256, 0, stream>>>(
        x_bf, wa_bf, q_ws, k_ws, v_ws, nullptr, nullptr, M, 3 * C_, C_);
    attn<<<dim3(T_ / 128, B_ * NH_), 256, 0, stream>>>(q_ws, k_ws, v_ws);
    gemm_bt<1, 0><<<dim3(C_ / 128, M / 128), 256, 0, stream>>>(
        q_ws, wp_bf, d_out, nullptr, nullptr, nullptr, probe, M, C_, C_);
  } else {
    gemm_bt<0, 1><<<dim3(3 * C_ / 128, M / 128), 256, 0, stream>>>(
        x, W_attn, q_ws, k_ws, v_ws, probe, nullptr, M, 3 * C_, C_);
    attn<<<dim3(T_ / 128, B_ * NH_), 256, 0, stream>>>(q_ws, k_ws, v_ws);
    gemm_bt<1, 0><<<dim3(C_ / 128, M / 128), 256, 0, stream>>>(
        q_ws, W_proj, d_out, nullptr, nullptr, probe, probe, M, C_, C_);
  }
}

// Round 4
// 300.296 us; speedup vs baseline: 1.0780x; 1.0691x over previous
//
#include <hip/hip_runtime.h>
#include <hip/hip_bf16.h>
#include <stdint.h>

// ============================================================================
// MultiAttentionWithGating — compression branch (_kc/_vc) is DEAD CODE.
// Pipeline: qkv = x@W_attn^T ; causal SDPA (16 heads, hs=64) ; out = y@W_proj^T
// Inputs fp32 (runtime-probed); internal bf16 MFMA, fp32 accum.
//
// ROUND 10 (attn 110us; all pipes <33%, occupancy 15% -> latency/serial-chain
// bound, NOT pipe bound):  [3rd submit: two container failures were infra
// (npz push timeout); device-side audit found no deadlock/OOB/race]
//  - Split-K flash attention. Fixed-max softmax (exp2(S-32)) makes partial
//    (O,l) over disjoint key ranges DIRECTLY ADDITIVE -> no max merging.
//    Each (bh,qb) is cut into <=16-tile key chunks (1024 keys): serial chain
//    32 -> 16 tiles; grid 16x64 -> 24x64 near-uniform blocks.
//  - x-order table: XCD residue classes each get tile-counts {16,16,2}/
//    {16,14,4}/{16,12,6}/{16,10,8} = 34 exactly; long chunks dispatch first.
//  - qb>=8 chunks write f32 partial O/l to workspace (+32.5 MiB, guarded by
//    ws_size; falls back to round-9 single-chunk schedule); attn_combine
//    (512 tiny blocks) sums partials, normalizes, writes y.
//  - Per-tile inner loop unchanged from round 8/9 for attribution.
// ============================================================================

typedef __bf16 bf16x8 __attribute__((ext_vector_type(8)));
typedef float f32x4 __attribute__((ext_vector_type(4)));
typedef __hip_bfloat16 bf16;

#define B_ 4
#define T_ 2048
#define C_ 1024
#define NH_ 16
#define HS_ 64
#define NEG_BIG (-30000.0f)
#define SCALE_LOG2E 0.180336880111f  // (1/sqrt(64)) * log2(e)

// Wave-uniform dtype probe on x (fp32 vs bf16), verified round 4.
__device__ __forceinline__ bool detect_fp32(const unsigned short* px) {
  const int lane = threadIdx.x & 63;
  const unsigned short u = px[2 * lane];
  const int e = (u >> 7) & 0xff;
  const bool plausible = (e >= 117) && (e <= 137);
  return __popcll(__ballot(plausible)) < 32;
}

// async global->LDS 16B per lane (m97). LDS dest: wave-uniform base + lane*16.
__device__ __forceinline__ void load_lds16(const bf16* g, bf16* l) {
  __builtin_amdgcn_global_load_lds(
      (const __attribute__((address_space(1))) void*)(uintptr_t)g,
      (__attribute__((address_space(3))) void*)(uintptr_t)l, 16, 0, 0);
}

// fp32 load of 8 elements -> 8 bf16 packed in uint4.
__device__ __forceinline__ uint4 ld8f(const void* base, size_t elt) {
  const float* fp = (const float*)base + elt;
  float4 f0 = *(const float4*)(fp);
  float4 f1 = *(const float4*)(fp + 4);
  union { bf16 h[8]; uint4 u; } r;
  r.h[0] = __float2bfloat16(f0.x); r.h[1] = __float2bfloat16(f0.y);
  r.h[2] = __float2bfloat16(f0.z); r.h[3] = __float2bfloat16(f0.w);
  r.h[4] = __float2bfloat16(f1.x); r.h[5] = __float2bfloat16(f1.y);
  r.h[6] = __float2bfloat16(f1.z); r.h[7] = __float2bfloat16(f1.w);
  return r.u;
}

// ----------------------------------------------------------------------------
// One-shot fp32->bf16 conversion of x, W_attn, W_proj (8 elems/thread).
// ----------------------------------------------------------------------------
__global__ __launch_bounds__(256) void convert3(
    const void* __restrict__ x, const void* __restrict__ wa,
    const void* __restrict__ wp, bf16* __restrict__ xb, bf16* __restrict__ wab,
    bf16* __restrict__ wpb, const unsigned short* __restrict__ probe) {
  const bool f32 = detect_fp32(probe);
  int blk = blockIdx.x;
  const void* src;
  bf16* dst;
  if (blk < 4096) {
    src = x; dst = xb;
  } else if (blk < 4096 + 1536) {
    blk -= 4096; src = wa; dst = wab;
  } else {
    blk -= 4096 + 1536; src = wp; dst = wpb;
  }
  const size_t i = ((size_t)blk * 256 + threadIdx.x) * 8;
  if (f32)
    *(uint4*)(dst + i) = ld8f(src, i);
  else
    *(uint4*)(dst + i) = *(const uint4*)((const bf16*)src + i);
}

// ----------------------------------------------------------------------------
// gemm_bt (round 7, unchanged): 128x128 tile, BK=32, global_load_lds staging
// on the bf16 path, fp32 reg-staging fallback.
// ----------------------------------------------------------------------------
template <int IN_MODE, int OUT_MODE>
__global__ __launch_bounds__(256, 2) void gemm_bt(
    const void* __restrict__ A, const void* __restrict__ B, void* __restrict__ C,
    bf16* __restrict__ k_ws, bf16* __restrict__ v_ws,
    const unsigned short* __restrict__ in_probe,
    const unsigned short* __restrict__ out_probe, int M, int N, int K) {
  __shared__ bf16 As[128 * 32];
  __shared__ bf16 Bs[128 * 32];

  const bool f32b = in_probe ? detect_fp32(in_probe) : false;
  const bool f32a = (IN_MODE == 0) && f32b;
  const bool f32out =
      (OUT_MODE == 0) && (out_probe ? detect_fp32(out_probe) : false);

  const int tid = threadIdx.x;
  const int lane = tid & 63;
  const int wid = tid >> 6;
  const int quad = lane >> 4;
  const int col = lane & 15;
  const int m0 = blockIdx.y * 128;
  const int n0 = blockIdx.x * 128;
  const int wm = (wid >> 1) * 64;
  const int wn = (wid & 1) * 64;
  const bool vsec = (OUT_MODE == 1) && ((n0 >> 10) == 2);

  const size_t arow = (size_t)(m0 + (tid >> 2));
  const size_t brow = (size_t)(n0 + (tid >> 2));
  const int chunk = (tid & 3) * 8;

  f32x4 acc[4][4] = {};

  for (int k0 = 0; k0 < K; k0 += 32) {
    const bf16* ap0;
    const bf16* ap1;
    if (IN_MODE == 0) {
      ap0 = (const bf16*)A + arow * K + chunk + k0;
      ap1 = (const bf16*)A + (arow + 64) * K + chunk + k0;
    } else {
      const int b = m0 >> 11;
      const int tloc = (m0 & 2047) + (tid >> 2);
      const size_t aoff = ((((size_t)b * NH_) + (k0 >> 6)) * T_ + tloc) * HS_ +
                          (k0 & 32) + chunk;
      ap0 = (const bf16*)A + aoff;
      ap1 = (const bf16*)A + aoff + (size_t)64 * HS_;
    }

    uint4 a0, a1, b0, b1;
    if (f32a) {
      a0 = ld8f(A, arow * K + chunk + k0);
      a1 = ld8f(A, (arow + 64) * K + chunk + k0);
    }
    if (f32b) {
      b0 = ld8f(B, brow * K + chunk + k0);
      b1 = ld8f(B, (brow + 64) * K + chunk + k0);
    }

    __syncthreads();
    if (f32a) {
      *(uint4*)(As + tid * 8) = a0;
      *(uint4*)(As + 2048 + tid * 8) = a1;
    } else {
      load_lds16(ap0, As + tid * 8);
      load_lds16(ap1, As + 2048 + tid * 8);
    }
    if (f32b) {
      *(uint4*)(Bs + tid * 8) = b0;
      *(uint4*)(Bs + 2048 + tid * 8) = b1;
    } else {
      load_lds16((const bf16*)B + brow * K + chunk + k0, Bs + tid * 8);
      load_lds16((const bf16*)B + (brow + 64) * K + chunk + k0,
                 Bs + 2048 + tid * 8);
    }
    __syncthreads();

    bf16x8 af[4], bfr[4];
#pragma unroll
    for (int t = 0; t < 4; ++t) {
      af[t] = *(const bf16x8*)(As + (wm + t * 16 + col) * 32 + quad * 8);
      bfr[t] = *(const bf16x8*)(Bs + (wn + t * 16 + col) * 32 + quad * 8);
    }
    if (vsec) {
#pragma unroll
      for (int tm = 0; tm < 4; ++tm)
#pragma unroll
        for (int tn = 0; tn < 4; ++tn)
          acc[tm][tn] = __builtin_amdgcn_mfma_f32_16x16x32_bf16(
              bfr[tn], af[tm], acc[tm][tn], 0, 0, 0);
    } else {
#pragma unroll
      for (int tm = 0; tm < 4; ++tm)
#pragma unroll
        for (int tn = 0; tn < 4; ++tn)
          acc[tm][tn] = __builtin_amdgcn_mfma_f32_16x16x32_bf16(
              af[tm], bfr[tn], acc[tm][tn], 0, 0, 0);
    }
  }

  if (OUT_MODE == 0) {
#pragma unroll
    for (int tm = 0; tm < 4; ++tm) {
      const int mrow = m0 + wm + tm * 16 + quad * 4;
#pragma unroll
      for (int tn = 0; tn < 4; ++tn) {
        const int ncol = n0 + wn + tn * 16 + col;
#pragma unroll
        for (int r = 0; r < 4; ++r) {
          if (f32out)
            ((float*)C)[(size_t)(mrow + r) * N + ncol] = acc[tm][tn][r];
          else
            ((bf16*)C)[(size_t)(mrow + r) * N + ncol] =
                __float2bfloat16(acc[tm][tn][r]);
        }
      }
    }
  } else if (vsec) {
    const int b = m0 >> 11;
#pragma unroll
    for (int tm = 0; tm < 4; ++tm) {
      const int tloc = (m0 & 2047) + wm + tm * 16 + col;
#pragma unroll
      for (int tn = 0; tn < 4; ++tn) {
        const int vch = (n0 & (C_ - 1)) + wn + tn * 16 + quad * 4;
#pragma unroll
        for (int r = 0; r < 4; ++r) {
          const int h = (vch + r) >> 6, d = (vch + r) & 63;
          v_ws[(((size_t)b * NH_ + h) * HS_ + d) * T_ + tloc] =
              __float2bfloat16(acc[tm][tn][r]);
        }
      }
    }
  } else {
    const int sect = n0 >> 10;  // 0:q 1:k
    bf16* dst = (sect == 0) ? (bf16*)C : k_ws;
#pragma unroll
    for (int tm = 0; tm < 4; ++tm) {
      const int mrow = m0 + wm + tm * 16 + quad * 4;
#pragma unroll
      for (int tn = 0; tn < 4; ++tn) {
        const int c = (n0 + wn + tn * 16 + col) & (C_ - 1);
        const int h = c >> 6, d = c & 63;
#pragma unroll
        for (int r = 0; r < 4; ++r) {
          const int t = (mrow + r) & (T_ - 1);
          const int b = (mrow + r) >> 11;
          dst[(((size_t)b * NH_ + h) * T_ + t) * HS_ + d] =
              __float2bfloat16(acc[tm][tn][r]);
        }
      }
    }
  }
}

// ----------------------------------------------------------------------------
// MFMA flash attention (causal), fixed-max softmax. Block = one (b,h) x 128 q
// rows x ONE KEY CHUNK (<=16 tiles of 64 keys). 4 waves x 32 q rows.
// S^T via operand-swapped MFMA; P through per-wave LDS; l = P*ones via MFMA.
// Fixed max -> partial (O,l) of disjoint key chunks are additive:
//   SPLIT=1: qb>=8 has 2 chunks; each writes f32 partial O/l; combine kernel
//            sums + normalizes. qb<8 (single chunk) finalizes in-kernel.
//   SPLIT=0: round-9 single-chunk schedule (workspace-constrained fallback).
// ----------------------------------------------------------------------------
template <int SPLIT>
__global__ __launch_bounds__(256, 2) void attn(
    bf16* qy, const bf16* __restrict__ kws, const bf16* __restrict__ vws,
    float* __restrict__ po, float* __restrict__ pl) {
  __shared__ bf16 Ks[64 * 72];      // [key][d]
  __shared__ bf16 Vs[64 * 72];      // [d][key]
  __shared__ bf16 Ps[4][32 * 72];   // per-wave P [32 q][64 k], stride 72

  const int tid = threadIdx.x;
  const int lane = tid & 63;
  const int w = tid >> 6;
  const int quad = lane >> 4;
  const int col = lane & 15;
  const int x = (int)blockIdx.x;

  int qb, ck;
  if (SPLIT) {
    // x -> (qb, chunk) table packed in scalars (no scratch array, rule #20).
    // tiles per x (x%8 classes sum to 34): x0-7:16(qb8-15 c0); x8:qb7(16),
    // x9:qb15c1(16), x10:qb6(14), x11:qb14c1(14), x12:qb5(12), x13:qb13c1(12),
    // x14:qb4(10), x15:qb12c1(10), x16:qb0(2), x17:qb8c1(2), x18:qb1(4),
    // x19:qb9c1(4), x20:qb2(6), x21:qb10c1(6), x22:qb3(8), x23:qb11c1(8).
    const unsigned long long lo = 0xC4D5E6F7FEDCBA98ULL;  // qb nibbles x0..15
    const unsigned int hi = 0xB3A29180u;                  // qb nibbles x16..23
    const unsigned int cmask = 0x00AAAA00u;               // chunk bit per x
    qb = (x < 16) ? (int)((lo >> (4 * x)) & 15)
                  : (int)((hi >> (4 * (x - 16))) & 15);
    ck = (int)((cmask >> x) & 1);
  } else {
    const int gx = (int)gridDim.x;  // 16
    const int hx = gx >> 1;
    qb = (x < hx) ? (gx - 1 - x) : (x - hx);
    ck = 0;
  }

  const int bh = blockIdx.y;
  const size_t head_off = (size_t)bh * T_ * HS_;

  const int ntall = 2 * (qb + 1);
  const int kt0 = SPLIT ? ck * 16 : 0;
  const int ntiles = SPLIT ? min(ntall - kt0, 16) : ntall;

  // Q fragments for both subtiles, pre-scaled into exp2 domain
  const int qrow = qb * 128 + w * 32 + col;
  const bf16* qp = qy + head_off + (size_t)qrow * HS_ + quad * 8;
  bf16x8 qf0a = *(const bf16x8*)(qp);
  bf16x8 qf1a = *(const bf16x8*)(qp + 32);
  bf16x8 qf0b = *(const bf16x8*)(qp + 16 * HS_);
  bf16x8 qf1b = *(const bf16x8*)(qp + 16 * HS_ + 32);
#pragma unroll
  for (int j = 0; j < 8; ++j) {
    qf0a[j] = (__bf16)((float)qf0a[j] * SCALE_LOG2E);
    qf1a[j] = (__bf16)((float)qf1a[j] * SCALE_LOG2E);
    qf0b[j] = (__bf16)((float)qf0b[j] * SCALE_LOG2E);
    qf1b[j] = (__bf16)((float)qf1b[j] * SCALE_LOG2E);
  }

  bf16x8 onesf;
#pragma unroll
  for (int j = 0; j < 8; ++j) onesf[j] = (__bf16)1.0f;

  f32x4 oa[4] = {}, ob[4] = {};
  f32x4 lacca = {}, laccb = {};

  bf16* pw = &Ps[w][0];

  // staging map: rows srow, srow+32; chunk sch
  const int srow = tid >> 3, sch = tid & 7;
  const bf16* kg = kws + head_off + (size_t)(kt0 * 64 + srow) * HS_ + sch * 8;
  const bf16* vg = vws + ((size_t)bh * HS_ + srow) * T_ + kt0 * 64 + sch * 8;
  bf16* kl0 = Ks + srow * 72 + sch * 8;
  bf16* kl1 = Ks + (srow + 32) * 72 + sch * 8;
  bf16* vl0 = Vs + srow * 72 + sch * 8;
  bf16* vl1 = Vs + (srow + 32) * 72 + sch * 8;

  // prefetch tile 0
  uint4 kr0 = *(const uint4*)(kg);
  uint4 kr1 = *(const uint4*)(kg + (size_t)32 * HS_);
  uint4 vr0 = *(const uint4*)(vg);
  uint4 vr1 = *(const uint4*)(vg + (size_t)32 * T_);

  const int qga = qb * 128 + w * 32 + col;  // subtile-a global q row
  const int diag_start = 2 * qb;            // global tiles >= this need masking

  for (int kt = 0; kt < ntiles; ++kt) {
    const int ktg = kt0 + kt;
    const int k0 = ktg * 64;
    __syncthreads();
    *(uint4*)kl0 = kr0;
    *(uint4*)kl1 = kr1;
    *(uint4*)vl0 = vr0;
    *(uint4*)vl1 = vr1;
    __syncthreads();
    if (kt + 1 < ntiles) {  // prefetch next tile during compute
      kg += (size_t)64 * HS_;
      vg += 64;
      kr0 = *(const uint4*)(kg);
      kr1 = *(const uint4*)(kg + (size_t)32 * HS_);
      vr0 = *(const uint4*)(vg);
      vr1 = *(const uint4*)(vg + (size_t)32 * T_);
    }

    // ---- S^T - 32 = (K Q^T) - 32 : lane -> (key=quad*4+r, q=col) ----
    f32x4 sa[4], sb[4];
#pragma unroll
    for (int nt = 0; nt < 4; ++nt) {
      const bf16* kp = Ks + (nt * 16 + col) * 72 + quad * 8;
      bf16x8 kf0 = *(const bf16x8*)(kp);
      bf16x8 kf1 = *(const bf16x8*)(kp + 32);
      f32x4 a = {-32.0f, -32.0f, -32.0f, -32.0f};
      a = __builtin_amdgcn_mfma_f32_16x16x32_bf16(kf0, qf0a, a, 0, 0, 0);
      a = __builtin_amdgcn_mfma_f32_16x16x32_bf16(kf1, qf1a, a, 0, 0, 0);
      sa[nt] = a;
      f32x4 b = {-32.0f, -32.0f, -32.0f, -32.0f};
      b = __builtin_amdgcn_mfma_f32_16x16x32_bf16(kf0, qf0b, b, 0, 0, 0);
      b = __builtin_amdgcn_mfma_f32_16x16x32_bf16(kf1, qf1b, b, 0, 0, 0);
      sb[nt] = b;
    }

    // ---- causal mask (only tiles overlapping the diagonal) ----
    if (ktg >= diag_start) {
#pragma unroll
      for (int nt = 0; nt < 4; ++nt) {
        const int key = k0 + nt * 16 + quad * 4;
#pragma unroll
        for (int r = 0; r < 4; ++r) {
          if (key + r > qga) sa[nt][r] = NEG_BIG;
          if (key + r > qga + 16) sb[nt][r] = NEG_BIG;
        }
      }
    }

    // ---- P = exp2(S-32): 4 consecutive keys/lane -> packed b64 writes ----
#pragma unroll
    for (int nt = 0; nt < 4; ++nt) {
      union { ushort u[4]; uint2 v; } pa, pb;
#pragma unroll
      for (int r = 0; r < 4; ++r) {
        pa.u[r] = __bfloat16_as_ushort(__float2bfloat16(exp2f(sa[nt][r])));
        pb.u[r] = __bfloat16_as_ushort(__float2bfloat16(exp2f(sb[nt][r])));
      }
      *(uint2*)(pw + col * 72 + nt * 16 + quad * 4) = pa.v;
      *(uint2*)(pw + (col + 16) * 72 + nt * 16 + quad * 4) = pb.v;
    }

    __asm__ __volatile__("s_waitcnt lgkmcnt(0)" ::: "memory");  // P visible

    // ---- O += P V ; l += P*ones (V-frags shared across subtiles) ----
#pragma unroll
    for (int half = 0; half < 2; ++half) {
      bf16x8 pfa = *(const bf16x8*)(pw + col * 72 + half * 32 + quad * 8);
      bf16x8 pfb = *(const bf16x8*)(pw + (col + 16) * 72 + half * 32 + quad * 8);
      lacca = __builtin_amdgcn_mfma_f32_16x16x32_bf16(pfa, onesf, lacca, 0, 0, 0);
      laccb = __builtin_amdgcn_mfma_f32_16x16x32_bf16(pfb, onesf, laccb, 0, 0, 0);
#pragma unroll
      for (int dt = 0; dt < 4; ++dt) {
        bf16x8 vf = *(const bf16x8*)(Vs + (dt * 16 + col) * 72 + half * 32 +
                                     quad * 8);
        oa[dt] = __builtin_amdgcn_mfma_f32_16x16x32_bf16(pfa, vf, oa[dt], 0, 0, 0);
        ob[dt] = __builtin_amdgcn_mfma_f32_16x16x32_bf16(pfb, vf, ob[dt], 0, 0, 0);
      }
    }
  }

  const bool dosplit = SPLIT && (qb >= 8);
  if (!dosplit) {
    // ---- finalize: y overwrites this wave's own q rows (head layout) ----
    float inva[4], invb[4];
#pragma unroll
    for (int r = 0; r < 4; ++r) {
      inva[r] = 1.0f / lacca[r];
      invb[r] = 1.0f / laccb[r];
    }
#pragma unroll
    for (int dt = 0; dt < 4; ++dt)
#pragma unroll
      for (int r = 0; r < 4; ++r) {
        const int qa = qb * 128 + w * 32 + quad * 4 + r;
        qy[head_off + (size_t)qa * HS_ + dt * 16 + col] =
            __float2bfloat16(oa[dt][r] * inva[r]);
        qy[head_off + (size_t)(qa + 16) * HS_ + dt * 16 + col] =
            __float2bfloat16(ob[dt][r] * invb[r]);
      }
  } else {
    // ---- write f32 partials; combine kernel finishes ----
    const int slot = ((qb - 8) * 64 + bh) * 2 + ck;
    float* o = po + (size_t)slot * (128 * 64);
#pragma unroll
    for (int dt = 0; dt < 4; ++dt)
#pragma unroll
      for (int r = 0; r < 4; ++r) {
        const int qa = w * 32 + quad * 4 + r;  // local q row in [0,128)
        o[(size_t)qa * 64 + dt * 16 + col] = oa[dt][r];
        o[(size_t)(qa + 16) * 64 + dt * 16 + col] = ob[dt][r];
      }
    if (col == 0) {
      float* lp = pl + (size_t)slot * 128;
#pragma unroll
      for (int r = 0; r < 4; ++r) {
        lp[w * 32 + quad * 4 + r] = lacca[r];
        lp[w * 32 + 16 + quad * 4 + r] = laccb[r];
      }
    }
  }
}

// ----------------------------------------------------------------------------
// Combine: for qb>=8, y = (O0+O1)/(l0+l1). One block per (qb,bh): 256 threads,
// thread -> (q = tid>>1, 32 d's). Memory-bound, ~42 MB total.
// ----------------------------------------------------------------------------
__global__ __launch_bounds__(256) void attn_combine(
    bf16* __restrict__ qy, const float* __restrict__ po,
    const float* __restrict__ pl) {
  const int qb = 8 + (int)blockIdx.x;  // 8..15
  const int bh = (int)blockIdx.y;
  const int pair = ((qb - 8) * 64 + bh) * 2;
  const float* o0 = po + (size_t)pair * (128 * 64);
  const float* o1 = o0 + 128 * 64;
  const float* l0 = pl + (size_t)pair * 128;
  const float* l1 = l0 + 128;
  const int q = threadIdx.x >> 1;
  const int d0 = (threadIdx.x & 1) * 32;
  const float inv = 1.0f / (l0[q] + l1[q]);
  const size_t base =
      (size_t)bh * T_ * HS_ + (size_t)(qb * 128 + q) * HS_ + d0;
  const size_t ob = (size_t)q * 64 + d0;
#pragma unroll
  for (int j0 = 0; j0 < 32; j0 += 8) {
    union { bf16 h[8]; uint4 u; } out;
#pragma unroll
    for (int j = 0; j < 8; ++j)
      out.h[j] = __float2bfloat16((o0[ob + j0 + j] + o1[ob + j0 + j]) * inv);
    *(uint4*)(qy + base + j0) = out.u;
  }
}

// ----------------------------------------------------------------------------
extern "C" void kernel_launch(void* const* d_in, const int* in_sizes, int n_in,
                              void* d_out, int out_size, void* d_ws, size_t ws_size,
                              hipStream_t stream) {
  const void* x = d_in[0];       // [4,2048,1024] fp32 (probed)
  const void* W_attn = d_in[1];  // [3072,1024]
  const void* W_proj = d_in[2];  // [1024,1024]
  const unsigned short* probe = (const unsigned short*)d_in[0];
  // d_in[3..6]: dead code in the reference.

  const size_t qkv_elems = (size_t)B_ * NH_ * T_ * HS_;  // 8388608
  const size_t xe = (size_t)B_ * T_ * C_;                // 8388608
  const size_t wae = (size_t)3 * C_ * C_;                // 3145728
  const size_t wpe = (size_t)C_ * C_;                    // 1048576

  bf16* q_ws = (bf16*)d_ws;
  bf16* k_ws = q_ws + qkv_elems;
  bf16* v_ws = k_ws + qkv_elems;
  bf16* x_bf = v_ws + qkv_elems;
  bf16* wa_bf = x_bf + xe;
  bf16* wp_bf = wa_bf + wae;
  const size_t need = (3 * qkv_elems + xe + wae + wpe) * sizeof(bf16);  // 72 MiB

  // split-K partials: 1024 slots x (128x64 O + 128 l) f32 = 32.5 MiB
  float* po = (float*)(wp_bf + wpe);
  float* pl = po + (size_t)1024 * 128 * 64;
  const size_t need2 =
      need + ((size_t)1024 * 128 * 64 + (size_t)1024 * 128) * sizeof(float);

  const int M = B_ * T_;  // 8192

  if (ws_size >= need) {
    convert3<<<6144, 256, 0, stream>>>(x, W_attn, W_proj, x_bf, wa_bf, wp_bf,
                                       probe);
    gemm_bt<0, 1><<<dim3(3 * C_ / 128, M / 128), 256, 0, stream>>>(
        x_bf, wa_bf, q_ws, k_ws, v_ws, nullptr, nullptr, M, 3 * C_, C_);
    if (ws_size >= need2) {
      attn<1><<<dim3(24, B_ * NH_), 256, 0, stream>>>(q_ws, k_ws, v_ws, po, pl);
      attn_combine<<<dim3(8, B_ * NH_), 256, 0, stream>>>(q_ws, po, pl);
    } else {
      attn<0><<<dim3(T_ / 128, B_ * NH_), 256, 0, stream>>>(q_ws, k_ws, v_ws,
                                                            nullptr, nullptr);
    }
    gemm_bt<1, 0><<<dim3(C_ / 128, M / 128), 256, 0, stream>>>(
        q_ws, wp_bf, d_out, nullptr, nullptr, nullptr, probe, M, C_, C_);
  } else {
    gemm_bt<0, 1><<<dim3(3 * C_ / 128, M / 128), 256, 0, stream>>>(
        x, W_attn, q_ws, k_ws, v_ws, probe, nullptr, M, 3 * C_, C_);
    attn<0><<<dim3(T_ / 128, B_ * NH_), 256, 0, stream>>>(q_ws, k_ws, v_ws,
                                                          nullptr, nullptr);
    gemm_bt<1, 0><<<dim3(C_ / 128, M / 128), 256, 0, stream>>>(
        q_ws, W_proj, d_out, nullptr, nullptr, probe, probe, M, C_, C_);
  }
}

// Round 5
// 285.187 us; speedup vs baseline: 1.1351x; 1.0530x over previous
//
#include <hip/hip_runtime.h>
#include <hip/hip_bf16.h>
#include <stdint.h>

// ============================================================================
// MultiAttentionWithGating — compression branch (_kc/_vc) is DEAD CODE.
// Pipeline: qkv = x@W_attn^T ; causal SDPA (16 heads, hs=64) ; out = y@W_proj^T
// Inputs fp32 (runtime-probed); internal bf16 MFMA, fp32 accum.
//
// ROUND 11 (QKV gemm now the top dispatch: 100us = 515 TF, MfmaUtil 21%,
// all pipes idle -> exposed staging latency):
//  - gemm_bt K-loop re-pipelined per the T3-min 2-phase template: LDS double
//    buffer (2x16KiB), STAGE(t+1) issued into buf^1 BEFORE ds_read+MFMA of
//    tile t, ONE __syncthreads per step (was: issue->drain->compute with two
//    barriers and zero overlap). fp32 fallback reg-stages with the same
//    buffer lifecycle (reg-loads issued early, LDS writes after MFMA).
//  - attn split-K (round 10) + combine unchanged; epilogues unchanged.
// ============================================================================

typedef __bf16 bf16x8 __attribute__((ext_vector_type(8)));
typedef float f32x4 __attribute__((ext_vector_type(4)));
typedef __hip_bfloat16 bf16;

#define B_ 4
#define T_ 2048
#define C_ 1024
#define NH_ 16
#define HS_ 64
#define NEG_BIG (-30000.0f)
#define SCALE_LOG2E 0.180336880111f  // (1/sqrt(64)) * log2(e)

// Wave-uniform dtype probe on x (fp32 vs bf16), verified round 4.
__device__ __forceinline__ bool detect_fp32(const unsigned short* px) {
  const int lane = threadIdx.x & 63;
  const unsigned short u = px[2 * lane];
  const int e = (u >> 7) & 0xff;
  const bool plausible = (e >= 117) && (e <= 137);
  return __popcll(__ballot(plausible)) < 32;
}

// async global->LDS 16B per lane (m97). LDS dest: wave-uniform base + lane*16.
__device__ __forceinline__ void load_lds16(const bf16* g, bf16* l) {
  __builtin_amdgcn_global_load_lds(
      (const __attribute__((address_space(1))) void*)(uintptr_t)g,
      (__attribute__((address_space(3))) void*)(uintptr_t)l, 16, 0, 0);
}

// fp32 load of 8 elements -> 8 bf16 packed in uint4.
__device__ __forceinline__ uint4 ld8f(const void* base, size_t elt) {
  const float* fp = (const float*)base + elt;
  float4 f0 = *(const float4*)(fp);
  float4 f1 = *(const float4*)(fp + 4);
  union { bf16 h[8]; uint4 u; } r;
  r.h[0] = __float2bfloat16(f0.x); r.h[1] = __float2bfloat16(f0.y);
  r.h[2] = __float2bfloat16(f0.z); r.h[3] = __float2bfloat16(f0.w);
  r.h[4] = __float2bfloat16(f1.x); r.h[5] = __float2bfloat16(f1.y);
  r.h[6] = __float2bfloat16(f1.z); r.h[7] = __float2bfloat16(f1.w);
  return r.u;
}

// ----------------------------------------------------------------------------
// One-shot fp32->bf16 conversion of x, W_attn, W_proj (8 elems/thread).
// ----------------------------------------------------------------------------
__global__ __launch_bounds__(256) void convert3(
    const void* __restrict__ x, const void* __restrict__ wa,
    const void* __restrict__ wp, bf16* __restrict__ xb, bf16* __restrict__ wab,
    bf16* __restrict__ wpb, const unsigned short* __restrict__ probe) {
  const bool f32 = detect_fp32(probe);
  int blk = blockIdx.x;
  const void* src;
  bf16* dst;
  if (blk < 4096) {
    src = x; dst = xb;
  } else if (blk < 4096 + 1536) {
    blk -= 4096; src = wa; dst = wab;
  } else {
    blk -= 4096 + 1536; src = wp; dst = wpb;
  }
  const size_t i = ((size_t)blk * 256 + threadIdx.x) * 8;
  if (f32)
    *(uint4*)(dst + i) = ld8f(src, i);
  else
    *(uint4*)(dst + i) = *(const uint4*)((const bf16*)src + i);
}

// ----------------------------------------------------------------------------
// gemm_bt (round 11): 128x128 tile, BK=32, DOUBLE-BUFFERED LDS, 2-phase
// schedule — STAGE(t+1) issued before compute(t), one barrier per K-step.
// ----------------------------------------------------------------------------
template <int IN_MODE, int OUT_MODE>
__global__ __launch_bounds__(256, 2) void gemm_bt(
    const void* __restrict__ A, const void* __restrict__ B, void* __restrict__ C,
    bf16* __restrict__ k_ws, bf16* __restrict__ v_ws,
    const unsigned short* __restrict__ in_probe,
    const unsigned short* __restrict__ out_probe, int M, int N, int K) {
  __shared__ bf16 As[2][128 * 32];
  __shared__ bf16 Bs[2][128 * 32];

  const bool f32b = in_probe ? detect_fp32(in_probe) : false;
  const bool f32a = (IN_MODE == 0) && f32b;
  const bool f32out =
      (OUT_MODE == 0) && (out_probe ? detect_fp32(out_probe) : false);

  const int tid = threadIdx.x;
  const int lane = tid & 63;
  const int wid = tid >> 6;
  const int quad = lane >> 4;
  const int col = lane & 15;
  const int m0 = blockIdx.y * 128;
  const int n0 = blockIdx.x * 128;
  const int wm = (wid >> 1) * 64;
  const int wn = (wid & 1) * 64;
  const bool vsec = (OUT_MODE == 1) && ((n0 >> 10) == 2);

  const size_t arow = (size_t)(m0 + (tid >> 2));
  const size_t brow = (size_t)(n0 + (tid >> 2));
  const int chunk = (tid & 3) * 8;
  // second A-row staging offset: +64 rows
  const size_t astep = (IN_MODE == 0) ? (size_t)64 * K : (size_t)64 * HS_;

  f32x4 acc[4][4] = {};

  // A base pointer for K-step k0 (bf16 paths)
  auto a_ptr = [&](int k0) -> const bf16* {
    if (IN_MODE == 0) return (const bf16*)A + arow * K + chunk + k0;
    const int b = m0 >> 11;
    const int tloc = (m0 & 2047) + (tid >> 2);
    return (const bf16*)A +
           ((((size_t)b * NH_) + (k0 >> 6)) * T_ + tloc) * HS_ + (k0 & 32) +
           chunk;
  };

  // ---- prologue: stage k0=0 into buffer 0 ----
  if (f32a) {
    uint4 a0 = ld8f(A, arow * K + chunk);
    uint4 a1 = ld8f(A, (arow + 64) * K + chunk);
    *(uint4*)(&As[0][0] + tid * 8) = a0;
    *(uint4*)(&As[0][0] + 2048 + tid * 8) = a1;
  } else {
    const bf16* ap = a_ptr(0);
    load_lds16(ap, &As[0][0] + tid * 8);
    load_lds16(ap + astep, &As[0][0] + 2048 + tid * 8);
  }
  if (f32b) {
    uint4 b0 = ld8f(B, brow * K + chunk);
    uint4 b1 = ld8f(B, (brow + 64) * K + chunk);
    *(uint4*)(&Bs[0][0] + tid * 8) = b0;
    *(uint4*)(&Bs[0][0] + 2048 + tid * 8) = b1;
  } else {
    load_lds16((const bf16*)B + brow * K + chunk, &Bs[0][0] + tid * 8);
    load_lds16((const bf16*)B + (brow + 64) * K + chunk,
               &Bs[0][0] + 2048 + tid * 8);
  }
  __syncthreads();  // drains vmcnt+lgkm: tile 0 resident

  int cur = 0;
  for (int k0 = 0; k0 < K; k0 += 32) {
    const int kn = k0 + 32;
    const bool hasn = kn < K;
    const int nxt = cur ^ 1;

    // ---- issue STAGE(t+1) into buf^1 (overlaps with compute below) ----
    uint4 a0, a1, b0, b1;
    bool wra = false, wrb = false;
    if (hasn) {
      if (f32a) {
        a0 = ld8f(A, arow * K + chunk + kn);
        a1 = ld8f(A, (arow + 64) * K + chunk + kn);
        wra = true;
      } else {
        const bf16* ap = a_ptr(kn);
        load_lds16(ap, &As[nxt][0] + tid * 8);
        load_lds16(ap + astep, &As[nxt][0] + 2048 + tid * 8);
      }
      if (f32b) {
        b0 = ld8f(B, brow * K + chunk + kn);
        b1 = ld8f(B, (brow + 64) * K + chunk + kn);
        wrb = true;
      } else {
        load_lds16((const bf16*)B + brow * K + chunk + kn,
                   &Bs[nxt][0] + tid * 8);
        load_lds16((const bf16*)B + (brow + 64) * K + chunk + kn,
                   &Bs[nxt][0] + 2048 + tid * 8);
      }
    }

    // ---- compute tile t from buf[cur] ----
    bf16x8 af[4], bfr[4];
#pragma unroll
    for (int t = 0; t < 4; ++t) {
      af[t] = *(const bf16x8*)(&As[cur][0] + (wm + t * 16 + col) * 32 + quad * 8);
      bfr[t] = *(const bf16x8*)(&Bs[cur][0] + (wn + t * 16 + col) * 32 + quad * 8);
    }
    if (vsec) {
#pragma unroll
      for (int tm = 0; tm < 4; ++tm)
#pragma unroll
        for (int tn = 0; tn < 4; ++tn)
          acc[tm][tn] = __builtin_amdgcn_mfma_f32_16x16x32_bf16(
              bfr[tn], af[tm], acc[tm][tn], 0, 0, 0);
    } else {
#pragma unroll
      for (int tm = 0; tm < 4; ++tm)
#pragma unroll
        for (int tn = 0; tn < 4; ++tn)
          acc[tm][tn] = __builtin_amdgcn_mfma_f32_16x16x32_bf16(
              af[tm], bfr[tn], acc[tm][tn], 0, 0, 0);
    }

    // ---- fp32 reg-staged writes land in buf^1 after compute ----
    if (wra) {
      *(uint4*)(&As[nxt][0] + tid * 8) = a0;
      *(uint4*)(&As[nxt][0] + 2048 + tid * 8) = a1;
    }
    if (wrb) {
      *(uint4*)(&Bs[nxt][0] + tid * 8) = b0;
      *(uint4*)(&Bs[nxt][0] + 2048 + tid * 8) = b1;
    }
    __syncthreads();  // tile t+1 resident; everyone done reading buf[cur]
    cur = nxt;
  }

  if (OUT_MODE == 0) {
#pragma unroll
    for (int tm = 0; tm < 4; ++tm) {
      const int mrow = m0 + wm + tm * 16 + quad * 4;
#pragma unroll
      for (int tn = 0; tn < 4; ++tn) {
        const int ncol = n0 + wn + tn * 16 + col;
#pragma unroll
        for (int r = 0; r < 4; ++r) {
          if (f32out)
            ((float*)C)[(size_t)(mrow + r) * N + ncol] = acc[tm][tn][r];
          else
            ((bf16*)C)[(size_t)(mrow + r) * N + ncol] =
                __float2bfloat16(acc[tm][tn][r]);
        }
      }
    }
  } else if (vsec) {
    const int b = m0 >> 11;
#pragma unroll
    for (int tm = 0; tm < 4; ++tm) {
      const int tloc = (m0 & 2047) + wm + tm * 16 + col;
#pragma unroll
      for (int tn = 0; tn < 4; ++tn) {
        const int vch = (n0 & (C_ - 1)) + wn + tn * 16 + quad * 4;
#pragma unroll
        for (int r = 0; r < 4; ++r) {
          const int h = (vch + r) >> 6, d = (vch + r) & 63;
          v_ws[(((size_t)b * NH_ + h) * HS_ + d) * T_ + tloc] =
              __float2bfloat16(acc[tm][tn][r]);
        }
      }
    }
  } else {
    const int sect = n0 >> 10;  // 0:q 1:k
    bf16* dst = (sect == 0) ? (bf16*)C : k_ws;
#pragma unroll
    for (int tm = 0; tm < 4; ++tm) {
      const int mrow = m0 + wm + tm * 16 + quad * 4;
#pragma unroll
      for (int tn = 0; tn < 4; ++tn) {
        const int c = (n0 + wn + tn * 16 + col) & (C_ - 1);
        const int h = c >> 6, d = c & 63;
#pragma unroll
        for (int r = 0; r < 4; ++r) {
          const int t = (mrow + r) & (T_ - 1);
          const int b = (mrow + r) >> 11;
          dst[(((size_t)b * NH_ + h) * T_ + t) * HS_ + d] =
              __float2bfloat16(acc[tm][tn][r]);
        }
      }
    }
  }
}

// ----------------------------------------------------------------------------
// MFMA flash attention (causal), fixed-max softmax. Block = one (b,h) x 128 q
// rows x ONE KEY CHUNK (<=16 tiles of 64 keys). 4 waves x 32 q rows.
// S^T via operand-swapped MFMA; P through per-wave LDS; l = P*ones via MFMA.
// Fixed max -> partial (O,l) of disjoint key chunks are additive:
//   SPLIT=1: qb>=8 has 2 chunks; each writes f32 partial O/l; combine kernel
//            sums + normalizes. qb<8 (single chunk) finalizes in-kernel.
//   SPLIT=0: round-9 single-chunk schedule (workspace-constrained fallback).
// ----------------------------------------------------------------------------
template <int SPLIT>
__global__ __launch_bounds__(256, 2) void attn(
    bf16* qy, const bf16* __restrict__ kws, const bf16* __restrict__ vws,
    float* __restrict__ po, float* __restrict__ pl) {
  __shared__ bf16 Ks[64 * 72];      // [key][d]
  __shared__ bf16 Vs[64 * 72];      // [d][key]
  __shared__ bf16 Ps[4][32 * 72];   // per-wave P [32 q][64 k], stride 72

  const int tid = threadIdx.x;
  const int lane = tid & 63;
  const int w = tid >> 6;
  const int quad = lane >> 4;
  const int col = lane & 15;
  const int x = (int)blockIdx.x;

  int qb, ck;
  if (SPLIT) {
    // x -> (qb, chunk) table packed in scalars (no scratch array, rule #20).
    // tiles per x (x%8 classes sum to 34): x0-7:16(qb8-15 c0); x8:qb7(16),
    // x9:qb15c1(16), x10:qb6(14), x11:qb14c1(14), x12:qb5(12), x13:qb13c1(12),
    // x14:qb4(10), x15:qb12c1(10), x16:qb0(2), x17:qb8c1(2), x18:qb1(4),
    // x19:qb9c1(4), x20:qb2(6), x21:qb10c1(6), x22:qb3(8), x23:qb11c1(8).
    const unsigned long long lo = 0xC4D5E6F7FEDCBA98ULL;  // qb nibbles x0..15
    const unsigned int hi = 0xB3A29180u;                  // qb nibbles x16..23
    const unsigned int cmask = 0x00AAAA00u;               // chunk bit per x
    qb = (x < 16) ? (int)((lo >> (4 * x)) & 15)
                  : (int)((hi >> (4 * (x - 16))) & 15);
    ck = (int)((cmask >> x) & 1);
  } else {
    const int gx = (int)gridDim.x;  // 16
    const int hx = gx >> 1;
    qb = (x < hx) ? (gx - 1 - x) : (x - hx);
    ck = 0;
  }

  const int bh = blockIdx.y;
  const size_t head_off = (size_t)bh * T_ * HS_;

  const int ntall = 2 * (qb + 1);
  const int kt0 = SPLIT ? ck * 16 : 0;
  const int ntiles = SPLIT ? min(ntall - kt0, 16) : ntall;

  // Q fragments for both subtiles, pre-scaled into exp2 domain
  const int qrow = qb * 128 + w * 32 + col;
  const bf16* qp = qy + head_off + (size_t)qrow * HS_ + quad * 8;
  bf16x8 qf0a = *(const bf16x8*)(qp);
  bf16x8 qf1a = *(const bf16x8*)(qp + 32);
  bf16x8 qf0b = *(const bf16x8*)(qp + 16 * HS_);
  bf16x8 qf1b = *(const bf16x8*)(qp + 16 * HS_ + 32);
#pragma unroll
  for (int j = 0; j < 8; ++j) {
    qf0a[j] = (__bf16)((float)qf0a[j] * SCALE_LOG2E);
    qf1a[j] = (__bf16)((float)qf1a[j] * SCALE_LOG2E);
    qf0b[j] = (__bf16)((float)qf0b[j] * SCALE_LOG2E);
    qf1b[j] = (__bf16)((float)qf1b[j] * SCALE_LOG2E);
  }

  bf16x8 onesf;
#pragma unroll
  for (int j = 0; j < 8; ++j) onesf[j] = (__bf16)1.0f;

  f32x4 oa[4] = {}, ob[4] = {};
  f32x4 lacca = {}, laccb = {};

  bf16* pw = &Ps[w][0];

  // staging map: rows srow, srow+32; chunk sch
  const int srow = tid >> 3, sch = tid & 7;
  const bf16* kg = kws + head_off + (size_t)(kt0 * 64 + srow) * HS_ + sch * 8;
  const bf16* vg = vws + ((size_t)bh * HS_ + srow) * T_ + kt0 * 64 + sch * 8;
  bf16* kl0 = Ks + srow * 72 + sch * 8;
  bf16* kl1 = Ks + (srow + 32) * 72 + sch * 8;
  bf16* vl0 = Vs + srow * 72 + sch * 8;
  bf16* vl1 = Vs + (srow + 32) * 72 + sch * 8;

  // prefetch tile 0
  uint4 kr0 = *(const uint4*)(kg);
  uint4 kr1 = *(const uint4*)(kg + (size_t)32 * HS_);
  uint4 vr0 = *(const uint4*)(vg);
  uint4 vr1 = *(const uint4*)(vg + (size_t)32 * T_);

  const int qga = qb * 128 + w * 32 + col;  // subtile-a global q row
  const int diag_start = 2 * qb;            // global tiles >= this need masking

  for (int kt = 0; kt < ntiles; ++kt) {
    const int ktg = kt0 + kt;
    const int k0 = ktg * 64;
    __syncthreads();
    *(uint4*)kl0 = kr0;
    *(uint4*)kl1 = kr1;
    *(uint4*)vl0 = vr0;
    *(uint4*)vl1 = vr1;
    __syncthreads();
    if (kt + 1 < ntiles) {  // prefetch next tile during compute
      kg += (size_t)64 * HS_;
      vg += 64;
      kr0 = *(const uint4*)(kg);
      kr1 = *(const uint4*)(kg + (size_t)32 * HS_);
      vr0 = *(const uint4*)(vg);
      vr1 = *(const uint4*)(vg + (size_t)32 * T_);
    }

    // ---- S^T - 32 = (K Q^T) - 32 : lane -> (key=quad*4+r, q=col) ----
    f32x4 sa[4], sb[4];
#pragma unroll
    for (int nt = 0; nt < 4; ++nt) {
      const bf16* kp = Ks + (nt * 16 + col) * 72 + quad * 8;
      bf16x8 kf0 = *(const bf16x8*)(kp);
      bf16x8 kf1 = *(const bf16x8*)(kp + 32);
      f32x4 a = {-32.0f, -32.0f, -32.0f, -32.0f};
      a = __builtin_amdgcn_mfma_f32_16x16x32_bf16(kf0, qf0a, a, 0, 0, 0);
      a = __builtin_amdgcn_mfma_f32_16x16x32_bf16(kf1, qf1a, a, 0, 0, 0);
      sa[nt] = a;
      f32x4 b = {-32.0f, -32.0f, -32.0f, -32.0f};
      b = __builtin_amdgcn_mfma_f32_16x16x32_bf16(kf0, qf0b, b, 0, 0, 0);
      b = __builtin_amdgcn_mfma_f32_16x16x32_bf16(kf1, qf1b, b, 0, 0, 0);
      sb[nt] = b;
    }

    // ---- causal mask (only tiles overlapping the diagonal) ----
    if (ktg >= diag_start) {
#pragma unroll
      for (int nt = 0; nt < 4; ++nt) {
        const int key = k0 + nt * 16 + quad * 4;
#pragma unroll
        for (int r = 0; r < 4; ++r) {
          if (key + r > qga) sa[nt][r] = NEG_BIG;
          if (key + r > qga + 16) sb[nt][r] = NEG_BIG;
        }
      }
    }

    // ---- P = exp2(S-32): 4 consecutive keys/lane -> packed b64 writes ----
#pragma unroll
    for (int nt = 0; nt < 4; ++nt) {
      union { ushort u[4]; uint2 v; } pa, pb;
#pragma unroll
      for (int r = 0; r < 4; ++r) {
        pa.u[r] = __bfloat16_as_ushort(__float2bfloat16(exp2f(sa[nt][r])));
        pb.u[r] = __bfloat16_as_ushort(__float2bfloat16(exp2f(sb[nt][r])));
      }
      *(uint2*)(pw + col * 72 + nt * 16 + quad * 4) = pa.v;
      *(uint2*)(pw + (col + 16) * 72 + nt * 16 + quad * 4) = pb.v;
    }

    __asm__ __volatile__("s_waitcnt lgkmcnt(0)" ::: "memory");  // P visible

    // ---- O += P V ; l += P*ones (V-frags shared across subtiles) ----
#pragma unroll
    for (int half = 0; half < 2; ++half) {
      bf16x8 pfa = *(const bf16x8*)(pw + col * 72 + half * 32 + quad * 8);
      bf16x8 pfb = *(const bf16x8*)(pw + (col + 16) * 72 + half * 32 + quad * 8);
      lacca = __builtin_amdgcn_mfma_f32_16x16x32_bf16(pfa, onesf, lacca, 0, 0, 0);
      laccb = __builtin_amdgcn_mfma_f32_16x16x32_bf16(pfb, onesf, laccb, 0, 0, 0);
#pragma unroll
      for (int dt = 0; dt < 4; ++dt) {
        bf16x8 vf = *(const bf16x8*)(Vs + (dt * 16 + col) * 72 + half * 32 +
                                     quad * 8);
        oa[dt] = __builtin_amdgcn_mfma_f32_16x16x32_bf16(pfa, vf, oa[dt], 0, 0, 0);
        ob[dt] = __builtin_amdgcn_mfma_f32_16x16x32_bf16(pfb, vf, ob[dt], 0, 0, 0);
      }
    }
  }

  const bool dosplit = SPLIT && (qb >= 8);
  if (!dosplit) {
    // ---- finalize: y overwrites this wave's own q rows (head layout) ----
    float inva[4], invb[4];
#pragma unroll
    for (int r = 0; r < 4; ++r) {
      inva[r] = 1.0f / lacca[r];
      invb[r] = 1.0f / laccb[r];
    }
#pragma unroll
    for (int dt = 0; dt < 4; ++dt)
#pragma unroll
      for (int r = 0; r < 4; ++r) {
        const int qa = qb * 128 + w * 32 + quad * 4 + r;
        qy[head_off + (size_t)qa * HS_ + dt * 16 + col] =
            __float2bfloat16(oa[dt][r] * inva[r]);
        qy[head_off + (size_t)(qa + 16) * HS_ + dt * 16 + col] =
            __float2bfloat16(ob[dt][r] * invb[r]);
      }
  } else {
    // ---- write f32 partials; combine kernel finishes ----
    const int slot = ((qb - 8) * 64 + bh) * 2 + ck;
    float* o = po + (size_t)slot * (128 * 64);
#pragma unroll
    for (int dt = 0; dt < 4; ++dt)
#pragma unroll
      for (int r = 0; r < 4; ++r) {
        const int qa = w * 32 + quad * 4 + r;  // local q row in [0,128)
        o[(size_t)qa * 64 + dt * 16 + col] = oa[dt][r];
        o[(size_t)(qa + 16) * 64 + dt * 16 + col] = ob[dt][r];
      }
    if (col == 0) {
      float* lp = pl + (size_t)slot * 128;
#pragma unroll
      for (int r = 0; r < 4; ++r) {
        lp[w * 32 + quad * 4 + r] = lacca[r];
        lp[w * 32 + 16 + quad * 4 + r] = laccb[r];
      }
    }
  }
}

// ----------------------------------------------------------------------------
// Combine: for qb>=8, y = (O0+O1)/(l0+l1). One block per (qb,bh): 256 threads,
// thread -> (q = tid>>1, 32 d's). Memory-bound, ~42 MB total.
// ----------------------------------------------------------------------------
__global__ __launch_bounds__(256) void attn_combine(
    bf16* __restrict__ qy, const float* __restrict__ po,
    const float* __restrict__ pl) {
  const int qb = 8 + (int)blockIdx.x;  // 8..15
  const int bh = (int)blockIdx.y;
  const int pair = ((qb - 8) * 64 + bh) * 2;
  const float* o0 = po + (size_t)pair * (128 * 64);
  const float* o1 = o0 + 128 * 64;
  const float* l0 = pl + (size_t)pair * 128;
  const float* l1 = l0 + 128;
  const int q = threadIdx.x >> 1;
  const int d0 = (threadIdx.x & 1) * 32;
  const float inv = 1.0f / (l0[q] + l1[q]);
  const size_t base =
      (size_t)bh * T_ * HS_ + (size_t)(qb * 128 + q) * HS_ + d0;
  const size_t ob = (size_t)q * 64 + d0;
#pragma unroll
  for (int j0 = 0; j0 < 32; j0 += 8) {
    union { bf16 h[8]; uint4 u; } out;
#pragma unroll
    for (int j = 0; j < 8; ++j)
      out.h[j] = __float2bfloat16((o0[ob + j0 + j] + o1[ob + j0 + j]) * inv);
    *(uint4*)(qy + base + j0) = out.u;
  }
}

// ----------------------------------------------------------------------------
extern "C" void kernel_launch(void* const* d_in, const int* in_sizes, int n_in,
                              void* d_out, int out_size, void* d_ws, size_t ws_size,
                              hipStream_t stream) {
  const void* x = d_in[0];       // [4,2048,1024] fp32 (probed)
  const void* W_attn = d_in[1];  // [3072,1024]
  const void* W_proj = d_in[2];  // [1024,1024]
  const unsigned short* probe = (const unsigned short*)d_in[0];
  // d_in[3..6]: dead code in the reference.

  const size_t qkv_elems = (size_t)B_ * NH_ * T_ * HS_;  // 8388608
  const size_t xe = (size_t)B_ * T_ * C_;                // 8388608
  const size_t wae = (size_t)3 * C_ * C_;                // 3145728
  const size_t wpe = (size_t)C_ * C_;                    // 1048576

  bf16* q_ws = (bf16*)d_ws;
  bf16* k_ws = q_ws + qkv_elems;
  bf16* v_ws = k_ws + qkv_elems;
  bf16* x_bf = v_ws + qkv_elems;
  bf16* wa_bf = x_bf + xe;
  bf16* wp_bf = wa_bf + wae;
  const size_t need = (3 * qkv_elems + xe + wae + wpe) * sizeof(bf16);  // 72 MiB

  // split-K partials: 1024 slots x (128x64 O + 128 l) f32 = 32.5 MiB
  float* po = (float*)(wp_bf + wpe);
  float* pl = po + (size_t)1024 * 128 * 64;
  const size_t need2 =
      need + ((size_t)1024 * 128 * 64 + (size_t)1024 * 128) * sizeof(float);

  const int M = B_ * T_;  // 8192

  if (ws_size >= need) {
    convert3<<<6144, 256, 0, stream>>>(x, W_attn, W_proj, x_bf, wa_bf, wp_bf,
                                       probe);
    gemm_bt<0, 1><<<dim3(3 * C_ / 128, M / 128), 256, 0, stream>>>(
        x_bf, wa_bf, q_ws, k_ws, v_ws, nullptr, nullptr, M, 3 * C_, C_);
    if (ws_size >= need2) {
      attn<1><<<dim3(24, B_ * NH_), 256, 0, stream>>>(q_ws, k_ws, v_ws, po, pl);
      attn_combine<<<dim3(8, B_ * NH_), 256, 0, stream>>>(q_ws, po, pl);
    } else {
      attn<0><<<dim3(T_ / 128, B_ * NH_), 256, 0, stream>>>(q_ws, k_ws, v_ws,
                                                            nullptr, nullptr);
    }
    gemm_bt<1, 0><<<dim3(C_ / 128, M / 128), 256, 0, stream>>>(
        q_ws, wp_bf, d_out, nullptr, nullptr, nullptr, probe, M, C_, C_);
  } else {
    gemm_bt<0, 1><<<dim3(3 * C_ / 128, M / 128), 256, 0, stream>>>(
        x, W_attn, q_ws, k_ws, v_ws, probe, nullptr, M, 3 * C_, C_);
    attn<0><<<dim3(T_ / 128, B_ * NH_), 256, 0, stream>>>(q_ws, k_ws, v_ws,
                                                          nullptr, nullptr);
    gemm_bt<1, 0><<<dim3(C_ / 128, M / 128), 256, 0, stream>>>(
        q_ws, W_proj, d_out, nullptr, nullptr, probe, probe, M, C_, C_);
  }
}